// Round 5
// baseline (31.978 us; speedup 1.0000x reference)
//
#include <hip/hip_runtime.h>

#define NSTROKES 64
#define NSAMP    50
#define CANVAS   512
#define HW       (CANVAS * CANVAS)
#define TPB      512   // 1 px/thread -> one 512-px row per block, 8 waves
#define NGROUPS  4
#define SPG      (NSTROKES / NGROUPS)   // 16 strokes per group
#define SPW      (SPG / 8)              // 2 strokes per wave
#define LSTRIDE  52                     // float2 slots per stroke list

// ---------------------------------------------------------------------------
// Kernel 1: per (row, stroke-group) block computes the group's affine map
//   c -> A*c + B per pixel. Ballot-based per-row sample compaction (no
//   atomics, no separate setup pass): wave w owns strokes {2w, 2w+1}; lane =
//   sample index; insertion index from ballot prefix-popcount; x-range of
//   kept samples via shuffle reduction.
// ---------------------------------------------------------------------------
__global__ __launch_bounds__(TPB) void raster_group_kernel(
    const float* __restrict__ strokes,   // (64,4,2)
    const float* __restrict__ widths,    // (64,)
    const float* __restrict__ colors,    // (64,3)
    float* __restrict__ ws)              // NGROUPS*4*HW floats
{
    __shared__ __align__(16) float2 slist[SPG * LSTRIDE];
    __shared__ int   scnt[SPG];
    __shared__ float sxmn[SPG];
    __shared__ float sxmx[SPG];

    const int tid  = threadIdx.x;
    const int wave = tid >> 6;
    const int lane = tid & 63;
    const int g     = blockIdx.y;
    const int sbase = g * SPG;
    const int y     = blockIdx.x;
    const float fy  = (float)y;

    // ---- stage A: compaction, SPW strokes per wave, lane = sample index
    #pragma unroll
    for (int i = 0; i < SPW; ++i) {
        const int s  = wave * SPW + i;        // local stroke id 0..15
        const int gs = sbase + s;

        float4 a = ((const float4*)strokes)[gs * 2];       // p0x,p0y,p1x,p1y
        float4 b = ((const float4*)strokes)[gs * 2 + 1];   // p2x,p2y,p3x,p3y
        const float S = (float)CANVAS;
        float c0x = a.x * S;
        float c1x = 3.0f * (a.z - a.x) * S;
        float c2x = 3.0f * (b.x - 2.0f * a.z + a.x) * S;
        float c3x = (b.z - 3.0f * b.x + 3.0f * a.z - a.x) * S;
        float c0y = a.y * S;
        float c1y = 3.0f * (a.w - a.y) * S;
        float c2y = 3.0f * (b.y - 2.0f * a.w + a.y) * S;
        float c3y = (b.w - 3.0f * b.y + 3.0f * a.w - a.y) * S;

        float w   = widths[gs];
        float cut = w + 10.0f;                 // alpha <= sigmoid(-20) ~ 2e-9 beyond

        float t  = (float)lane * (1.0f / (float)(NSAMP - 1));
        float px = fmaf(fmaf(fmaf(c3x, t, c2x), t, c1x), t, c0x);
        float py = fmaf(fmaf(fmaf(c3y, t, c2y), t, c1y), t, c0y);

        bool keep = (lane < NSAMP) && (fabsf(py - fy) <= cut);
        unsigned long long mask = __ballot(keep);
        int idx = __popcll(mask & ((1ull << lane) - 1ull));
        if (keep) slist[s * LSTRIDE + idx] = make_float2(px, py);

        float vmn = keep ? px : 1e30f;
        float vmx = keep ? px : -1e30f;
        #pragma unroll
        for (int off = 32; off; off >>= 1) {
            vmn = fminf(vmn, __shfl_xor(vmn, off));
            vmx = fmaxf(vmx, __shfl_xor(vmx, off));
        }
        if (lane == 0) {
            scnt[s] = __popcll(mask);
            sxmn[s] = vmn;
            sxmx[s] = vmx;
        }
    }
    __syncthreads();

    // ---- stage B: per-pixel min-dist over compacted lists, affine blend
    const float fx = (float)tid;    // 1 px per thread

    float A = 1.0f, br = 0.0f, bg = 0.0f, bb = 0.0f;

    for (int s = 0; s < SPG; ++s) {
        const int kc = scnt[s];
        if (kc == 0) continue;                 // whole row outside band

        const int gs = sbase + s;
        float w   = widths[gs];                // wave-uniform scalar load
        float cut = w + 10.0f;

        // exact x-range cull over kept samples (y handled by compaction);
        // wave spans 64 px -> tight granularity
        float ddx = fmaxf(fmaxf(sxmn[s] - fx, fx - sxmx[s]), 0.0f);
        if (__all(ddx > cut)) continue;

        float m = 1e30f;
        const float2* L = slist + s * LSTRIDE;

        int j = 0;
        for (; j + 2 <= kc; j += 2) {
            float4 q = *(const float4*)(L + j);   // 2 samples, broadcast read
            float dy0 = fy - q.y;
            float dy1 = fy - q.w;
            float da  = fx - q.x;
            float db  = fx - q.z;
            m = fminf(fminf(fmaf(da, da, dy0 * dy0),
                            fmaf(db, db, dy1 * dy1)), m);
        }
        if (j < kc) {
            float2 p = L[j];
            float dy = fy - p.y;
            float da = fx - p.x;
            m = fminf(fmaf(da, da, dy * dy), m);
        }

        float al = __builtin_amdgcn_rcpf(1.0f + __expf(2.0f * (sqrtf(m) - w)));
        float c0 = colors[3*gs], c1 = colors[3*gs+1], c2 = colors[3*gs+2];

        A  *= (1.0f - al);
        br  = fmaf(al, c0 - br, br);
        bg  = fmaf(al, c1 - bg, bg);
        bb  = fmaf(al, c2 - bb, bb);
    }

    const int base = y * CANVAS + tid;
    float* wp = ws + (size_t)g * 4 * HW;
    wp[0*HW + base] = A;
    wp[1*HW + base] = br;
    wp[2*HW + base] = bg;
    wp[3*HW + base] = bb;
}

// ---------------------------------------------------------------------------
// Kernel 2: fold the NGROUPS affine maps (in order) onto the white canvas.
// ---------------------------------------------------------------------------
__global__ __launch_bounds__(256) void combine_kernel(
    const float* __restrict__ ws, float* __restrict__ out)
{
    const int t    = blockIdx.x * 256 + threadIdx.x;   // HW/4 threads
    const int base = t * 4;

    float4 cr = make_float4(1.f,1.f,1.f,1.f);
    float4 cg = make_float4(1.f,1.f,1.f,1.f);
    float4 cb = make_float4(1.f,1.f,1.f,1.f);

    #pragma unroll
    for (int g = 0; g < NGROUPS; ++g) {
        const float* wp = ws + (size_t)g * 4 * HW;
        float4 A  = ((const float4*)(wp + 0*HW + base))[0];
        float4 Br = ((const float4*)(wp + 1*HW + base))[0];
        float4 Bg = ((const float4*)(wp + 2*HW + base))[0];
        float4 Bb = ((const float4*)(wp + 3*HW + base))[0];
        cr.x = fmaf(A.x, cr.x, Br.x); cr.y = fmaf(A.y, cr.y, Br.y);
        cr.z = fmaf(A.z, cr.z, Br.z); cr.w = fmaf(A.w, cr.w, Br.w);
        cg.x = fmaf(A.x, cg.x, Bg.x); cg.y = fmaf(A.y, cg.y, Bg.y);
        cg.z = fmaf(A.z, cg.z, Bg.z); cg.w = fmaf(A.w, cg.w, Bg.w);
        cb.x = fmaf(A.x, cb.x, Bb.x); cb.y = fmaf(A.y, cb.y, Bb.y);
        cb.z = fmaf(A.z, cb.z, Bb.z); cb.w = fmaf(A.w, cb.w, Bb.w);
    }

    ((float4*)(out + 0*HW + base))[0] = cr;
    ((float4*)(out + 1*HW + base))[0] = cg;
    ((float4*)(out + 2*HW + base))[0] = cb;
}

// ---------------------------------------------------------------------------
// Fallback (ws too small): round-1 direct kernel, known-good.
// ---------------------------------------------------------------------------
__global__ __launch_bounds__(128) void raster_direct_kernel(
    const float* __restrict__ strokes, const float* __restrict__ widths,
    const float* __restrict__ colors, float* __restrict__ out)
{
    __shared__ float2 spts[NSTROKES * NSAMP];
    __shared__ float4 sbb [NSTROKES];
    __shared__ float  swid[NSTROKES];
    __shared__ float4 scol[NSTROKES];

    const int tid = threadIdx.x;
    for (int k = tid; k < NSTROKES * NSAMP; k += 128) {
        int s = k / NSAMP;
        int j = k - s * NSAMP;
        float t  = (float)j * (1.0f / (float)(NSAMP - 1));
        float u  = 1.0f - t;
        float b0 = u*u*u, b1 = 3.f*u*u*t, b2 = 3.f*u*t*t, b3 = t*t*t;
        float4 a = ((const float4*)strokes)[s * 2];
        float4 b = ((const float4*)strokes)[s * 2 + 1];
        spts[k] = make_float2((b0*a.x + b1*a.z + b2*b.x + b3*b.z) * (float)CANVAS,
                              (b0*a.y + b1*a.w + b2*b.y + b3*b.w) * (float)CANVAS);
    }
    if (tid < NSTROKES) {
        float4 a = ((const float4*)strokes)[tid * 2];
        float4 b = ((const float4*)strokes)[tid * 2 + 1];
        sbb [tid] = make_float4(fminf(fminf(a.x,a.z),fminf(b.x,b.z)) * (float)CANVAS,
                                fminf(fminf(a.y,a.w),fminf(b.y,b.w)) * (float)CANVAS,
                                fmaxf(fmaxf(a.x,a.z),fmaxf(b.x,b.z)) * (float)CANVAS,
                                fmaxf(fmaxf(a.y,a.w),fmaxf(b.y,b.w)) * (float)CANVAS);
        swid[tid] = widths[tid];
        scol[tid] = make_float4(colors[3*tid], colors[3*tid+1], colors[3*tid+2], 0.0f);
    }
    __syncthreads();

    const int   y   = blockIdx.x;
    const int   x0  = tid * 4;
    const float fy  = (float)y;
    const float fx0 = (float)x0;
    const float fx1 = fx0+1.f, fx2 = fx0+2.f, fx3 = fx0+3.f;

    float cr0=1.f,cg0=1.f,cb0=1.f, cr1=1.f,cg1=1.f,cb1=1.f;
    float cr2=1.f,cg2=1.f,cb2=1.f, cr3=1.f,cg3=1.f,cb3=1.f;

    for (int s = 0; s < NSTROKES; ++s) {
        float4 bb = sbb[s];
        float  w  = swid[s];
        float ddx = fmaxf(fmaxf(bb.x - fx3, fx0 - bb.z), 0.0f);
        float ddy = fmaxf(fmaxf(bb.y - fy,  fy  - bb.w), 0.0f);
        float cut = w + 10.0f;
        if (__all((ddx*ddx + ddy*ddy) > cut*cut)) continue;

        float m0 = 1e30f, m1 = 1e30f, m2 = 1e30f, m3 = 1e30f;
        const float4* P4 = (const float4*)(spts + s * NSAMP);
        #pragma unroll
        for (int j = 0; j < NSAMP / 2; ++j) {
            float4 q = P4[j];
            float dy0 = fy - q.y; float t0 = dy0 * dy0;
            float dy1 = fy - q.w; float t1 = dy1 * dy1;
            { float da = fx0 - q.x, db = fx0 - q.z;
              m0 = fminf(fminf(fmaf(da,da,t0), fmaf(db,db,t1)), m0); }
            { float da = fx1 - q.x, db = fx1 - q.z;
              m1 = fminf(fminf(fmaf(da,da,t0), fmaf(db,db,t1)), m1); }
            { float da = fx2 - q.x, db = fx2 - q.z;
              m2 = fminf(fminf(fmaf(da,da,t0), fmaf(db,db,t1)), m2); }
            { float da = fx3 - q.x, db = fx3 - q.z;
              m3 = fminf(fminf(fmaf(da,da,t0), fmaf(db,db,t1)), m3); }
        }

        float4 col = scol[s];
        float a0 = __builtin_amdgcn_rcpf(1.0f + __expf(2.0f * (sqrtf(m0) - w)));
        float a1 = __builtin_amdgcn_rcpf(1.0f + __expf(2.0f * (sqrtf(m1) - w)));
        float a2 = __builtin_amdgcn_rcpf(1.0f + __expf(2.0f * (sqrtf(m2) - w)));
        float a3 = __builtin_amdgcn_rcpf(1.0f + __expf(2.0f * (sqrtf(m3) - w)));

        cr0 = fmaf(a0, col.x - cr0, cr0); cg0 = fmaf(a0, col.y - cg0, cg0); cb0 = fmaf(a0, col.z - cb0, cb0);
        cr1 = fmaf(a1, col.x - cr1, cr1); cg1 = fmaf(a1, col.y - cg1, cg1); cb1 = fmaf(a1, col.z - cb1, cb1);
        cr2 = fmaf(a2, col.x - cr2, cr2); cg2 = fmaf(a2, col.y - cg2, cg2); cb2 = fmaf(a2, col.z - cb2, cb2);
        cr3 = fmaf(a3, col.x - cr3, cr3); cg3 = fmaf(a3, col.y - cg3, cg3); cb3 = fmaf(a3, col.z - cb3, cb3);
    }

    const int base = y * CANVAS + x0;
    ((float4*)(out + 0*HW + base))[0] = make_float4(cr0, cr1, cr2, cr3);
    ((float4*)(out + 1*HW + base))[0] = make_float4(cg0, cg1, cg2, cg3);
    ((float4*)(out + 2*HW + base))[0] = make_float4(cb0, cb1, cb2, cb3);
}

extern "C" void kernel_launch(void* const* d_in, const int* in_sizes, int n_in,
                              void* d_out, int out_size, void* d_ws, size_t ws_size,
                              hipStream_t stream) {
    const float* strokes = (const float*)d_in[0];
    const float* widths  = (const float*)d_in[1];
    const float* colors  = (const float*)d_in[2];
    float* out = (float*)d_out;

    const size_t need = (size_t)NGROUPS * 4 * HW * sizeof(float);
    if (ws_size >= need) {
        raster_group_kernel<<<dim3(CANVAS, NGROUPS), dim3(TPB), 0, stream>>>(
            strokes, widths, colors, (float*)d_ws);
        combine_kernel<<<dim3(HW / 4 / 256), dim3(256), 0, stream>>>(
            (const float*)d_ws, out);
    } else {
        raster_direct_kernel<<<dim3(CANVAS), dim3(128), 0, stream>>>(
            strokes, widths, colors, out);
    }
}

// Round 6
// 26.517 us; speedup vs baseline: 1.2059x; 1.2059x over previous
//
#include <hip/hip_runtime.h>
#include <hip/hip_fp16.h>

#define NSTROKES 64
#define NSAMP    50
#define CANVAS   512
#define HW       (CANVAS * CANVAS)
#define TPB      256   // 2 px/thread -> one 512-px row per block, 4 waves
#define NGROUPS  4
#define SPG      (NSTROKES / NGROUPS)   // 16 strokes per group
#define SPW      (SPG / 4)              // 4 strokes per wave
#define LSTRIDE  52                     // float2 slots per stroke list

// ---------------------------------------------------------------------------
// Kernel 1: per (row, stroke-group) block computes the group's affine map
//   c -> A*c + B per pixel. Ballot-based compaction (no atomics): wave w owns
//   strokes {4w..4w+3}; lane = sample index; insertion index from ballot
//   prefix-popcount; x-range of kept samples via shuffle reduction; lane 0
//   stages width/color into LDS. Stage B: 2 px/thread (round-4 shape).
//   Workspace planes stored as f16 (half traffic for the combine pass).
// ---------------------------------------------------------------------------
__global__ __launch_bounds__(TPB) void raster_group_kernel(
    const float* __restrict__ strokes,   // (64,4,2)
    const float* __restrict__ widths,    // (64,)
    const float* __restrict__ colors,    // (64,3)
    __half* __restrict__ ws)             // NGROUPS*4*HW halves
{
    __shared__ __align__(16) float2 slist[SPG * LSTRIDE];
    __shared__ int    scnt[SPG];
    __shared__ float  sxmn[SPG];
    __shared__ float  sxmx[SPG];
    __shared__ float  swid[SPG];
    __shared__ float4 scol[SPG];

    const int tid  = threadIdx.x;
    const int wave = tid >> 6;
    const int lane = tid & 63;
    const int g     = blockIdx.y;
    const int sbase = g * SPG;
    const int y     = blockIdx.x;
    const float fy  = (float)y;

    // ---- stage A: compaction, SPW strokes per wave, lane = sample index
    #pragma unroll
    for (int i = 0; i < SPW; ++i) {
        const int s  = wave * SPW + i;        // local stroke id 0..15
        const int gs = sbase + s;

        float4 a = ((const float4*)strokes)[gs * 2];       // p0x,p0y,p1x,p1y
        float4 b = ((const float4*)strokes)[gs * 2 + 1];   // p2x,p2y,p3x,p3y
        const float S = (float)CANVAS;
        float c0x = a.x * S;
        float c1x = 3.0f * (a.z - a.x) * S;
        float c2x = 3.0f * (b.x - 2.0f * a.z + a.x) * S;
        float c3x = (b.z - 3.0f * b.x + 3.0f * a.z - a.x) * S;
        float c0y = a.y * S;
        float c1y = 3.0f * (a.w - a.y) * S;
        float c2y = 3.0f * (b.y - 2.0f * a.w + a.y) * S;
        float c3y = (b.w - 3.0f * b.y + 3.0f * a.w - a.y) * S;

        float w   = widths[gs];
        float cut = w + 10.0f;                 // alpha <= sigmoid(-20) ~ 2e-9 beyond

        float t  = (float)lane * (1.0f / (float)(NSAMP - 1));
        float px = fmaf(fmaf(fmaf(c3x, t, c2x), t, c1x), t, c0x);
        float py = fmaf(fmaf(fmaf(c3y, t, c2y), t, c1y), t, c0y);

        bool keep = (lane < NSAMP) && (fabsf(py - fy) <= cut);
        unsigned long long mask = __ballot(keep);
        int idx = __popcll(mask & ((1ull << lane) - 1ull));
        if (keep) slist[s * LSTRIDE + idx] = make_float2(px, py);

        float vmn = keep ? px : 1e30f;
        float vmx = keep ? px : -1e30f;
        #pragma unroll
        for (int off = 32; off; off >>= 1) {
            vmn = fminf(vmn, __shfl_xor(vmn, off));
            vmx = fmaxf(vmx, __shfl_xor(vmx, off));
        }
        if (lane == 0) {
            scnt[s] = __popcll(mask);
            sxmn[s] = vmn;
            sxmx[s] = vmx;
            swid[s] = w;
            scol[s] = make_float4(colors[3*gs], colors[3*gs+1], colors[3*gs+2], 0.0f);
        }
    }
    __syncthreads();

    // ---- stage B: per-pixel min-dist over compacted lists, affine blend
    const int   x0  = tid * 2;
    const float fx0 = (float)x0;
    const float fx1 = fx0 + 1.0f;

    float A0 = 1.f, A1 = 1.f;
    float br0=0.f,bg0=0.f,bb0=0.f, br1=0.f,bg1=0.f,bb1=0.f;

    for (int s = 0; s < SPG; ++s) {
        const int kc = scnt[s];
        if (kc == 0) continue;               // whole row outside band

        float w   = swid[s];
        float cut = w + 10.0f;

        // exact x-range cull over kept samples (y handled by compaction)
        float ddx = fmaxf(fmaxf(sxmn[s] - fx1, fx0 - sxmx[s]), 0.0f);
        if (__all(ddx > cut)) continue;

        float m0 = 1e30f, m1 = 1e30f;
        const float2* L = slist + s * LSTRIDE;

        int j = 0;
        for (; j + 2 <= kc; j += 2) {
            float4 q = *(const float4*)(L + j);   // 2 samples, broadcast read
            float dy0 = fy - q.y; float t0 = dy0 * dy0;
            float dy1 = fy - q.w; float t1 = dy1 * dy1;
            { float da = fx0 - q.x, db = fx0 - q.z;
              m0 = fminf(fminf(fmaf(da,da,t0), fmaf(db,db,t1)), m0); }
            { float da = fx1 - q.x, db = fx1 - q.z;
              m1 = fminf(fminf(fmaf(da,da,t0), fmaf(db,db,t1)), m1); }
        }
        if (j < kc) {
            float2 p = L[j];
            float dy = fy - p.y; float t0 = dy * dy;
            { float da = fx0 - p.x; m0 = fminf(fmaf(da,da,t0), m0); }
            { float da = fx1 - p.x; m1 = fminf(fmaf(da,da,t0), m1); }
        }

        float4 col = scol[s];
        float a0 = __builtin_amdgcn_rcpf(1.0f + __expf(2.0f * (sqrtf(m0) - w)));
        float a1 = __builtin_amdgcn_rcpf(1.0f + __expf(2.0f * (sqrtf(m1) - w)));

        A0 *= (1.0f - a0); A1 *= (1.0f - a1);
        br0 = fmaf(a0, col.x - br0, br0); bg0 = fmaf(a0, col.y - bg0, bg0); bb0 = fmaf(a0, col.z - bb0, bb0);
        br1 = fmaf(a1, col.x - br1, br1); bg1 = fmaf(a1, col.y - bg1, bg1); bb1 = fmaf(a1, col.z - bb1, bb1);
    }

    const int h2i = (y * CANVAS + x0) >> 1;   // half2 index
    __half* wp = ws + (size_t)g * 4 * HW;
    ((__half2*)(wp + 0*HW))[h2i] = __floats2half2_rn(A0, A1);
    ((__half2*)(wp + 1*HW))[h2i] = __floats2half2_rn(br0, br1);
    ((__half2*)(wp + 2*HW))[h2i] = __floats2half2_rn(bg0, bg1);
    ((__half2*)(wp + 3*HW))[h2i] = __floats2half2_rn(bb0, bb1);
}

// ---------------------------------------------------------------------------
// Kernel 2: fold the NGROUPS affine maps (in order) onto the white canvas.
// ---------------------------------------------------------------------------
__global__ __launch_bounds__(256) void combine_kernel(
    const __half* __restrict__ ws, float* __restrict__ out)
{
    const int t    = blockIdx.x * 256 + threadIdx.x;   // HW/4 threads
    const int base = t * 4;

    float4 cr = make_float4(1.f,1.f,1.f,1.f);
    float4 cg = make_float4(1.f,1.f,1.f,1.f);
    float4 cb = make_float4(1.f,1.f,1.f,1.f);

    #pragma unroll
    for (int g = 0; g < NGROUPS; ++g) {
        const __half* wp = ws + (size_t)g * 4 * HW;
        float2 Aa = __half22float2(((const __half2*)(wp + 0*HW))[t*2]);
        float2 Ab = __half22float2(((const __half2*)(wp + 0*HW))[t*2+1]);
        float2 Ra = __half22float2(((const __half2*)(wp + 1*HW))[t*2]);
        float2 Rb = __half22float2(((const __half2*)(wp + 1*HW))[t*2+1]);
        float2 Ga = __half22float2(((const __half2*)(wp + 2*HW))[t*2]);
        float2 Gb = __half22float2(((const __half2*)(wp + 2*HW))[t*2+1]);
        float2 Ba = __half22float2(((const __half2*)(wp + 3*HW))[t*2]);
        float2 Bb = __half22float2(((const __half2*)(wp + 3*HW))[t*2+1]);

        cr.x = fmaf(Aa.x, cr.x, Ra.x); cr.y = fmaf(Aa.y, cr.y, Ra.y);
        cr.z = fmaf(Ab.x, cr.z, Rb.x); cr.w = fmaf(Ab.y, cr.w, Rb.y);
        cg.x = fmaf(Aa.x, cg.x, Ga.x); cg.y = fmaf(Aa.y, cg.y, Ga.y);
        cg.z = fmaf(Ab.x, cg.z, Gb.x); cg.w = fmaf(Ab.y, cg.w, Gb.y);
        cb.x = fmaf(Aa.x, cb.x, Ba.x); cb.y = fmaf(Aa.y, cb.y, Ba.y);
        cb.z = fmaf(Ab.x, cb.z, Bb.x); cb.w = fmaf(Ab.y, cb.w, Bb.y);
    }

    ((float4*)(out + 0*HW + base))[0] = cr;
    ((float4*)(out + 1*HW + base))[0] = cg;
    ((float4*)(out + 2*HW + base))[0] = cb;
}

// ---------------------------------------------------------------------------
// Fallback (ws too small): round-1 direct kernel, known-good.
// ---------------------------------------------------------------------------
__global__ __launch_bounds__(128) void raster_direct_kernel(
    const float* __restrict__ strokes, const float* __restrict__ widths,
    const float* __restrict__ colors, float* __restrict__ out)
{
    __shared__ float2 spts[NSTROKES * NSAMP];
    __shared__ float4 sbb [NSTROKES];
    __shared__ float  swid[NSTROKES];
    __shared__ float4 scol[NSTROKES];

    const int tid = threadIdx.x;
    for (int k = tid; k < NSTROKES * NSAMP; k += 128) {
        int s = k / NSAMP;
        int j = k - s * NSAMP;
        float t  = (float)j * (1.0f / (float)(NSAMP - 1));
        float u  = 1.0f - t;
        float b0 = u*u*u, b1 = 3.f*u*u*t, b2 = 3.f*u*t*t, b3 = t*t*t;
        float4 a = ((const float4*)strokes)[s * 2];
        float4 b = ((const float4*)strokes)[s * 2 + 1];
        spts[k] = make_float2((b0*a.x + b1*a.z + b2*b.x + b3*b.z) * (float)CANVAS,
                              (b0*a.y + b1*a.w + b2*b.y + b3*b.w) * (float)CANVAS);
    }
    if (tid < NSTROKES) {
        float4 a = ((const float4*)strokes)[tid * 2];
        float4 b = ((const float4*)strokes)[tid * 2 + 1];
        sbb [tid] = make_float4(fminf(fminf(a.x,a.z),fminf(b.x,b.z)) * (float)CANVAS,
                                fminf(fminf(a.y,a.w),fminf(b.y,b.w)) * (float)CANVAS,
                                fmaxf(fmaxf(a.x,a.z),fmaxf(b.x,b.z)) * (float)CANVAS,
                                fmaxf(fmaxf(a.y,a.w),fmaxf(b.y,b.w)) * (float)CANVAS);
        swid[tid] = widths[tid];
        scol[tid] = make_float4(colors[3*tid], colors[3*tid+1], colors[3*tid+2], 0.0f);
    }
    __syncthreads();

    const int   y   = blockIdx.x;
    const int   x0  = tid * 4;
    const float fy  = (float)y;
    const float fx0 = (float)x0;
    const float fx1 = fx0+1.f, fx2 = fx0+2.f, fx3 = fx0+3.f;

    float cr0=1.f,cg0=1.f,cb0=1.f, cr1=1.f,cg1=1.f,cb1=1.f;
    float cr2=1.f,cg2=1.f,cb2=1.f, cr3=1.f,cg3=1.f,cb3=1.f;

    for (int s = 0; s < NSTROKES; ++s) {
        float4 bb = sbb[s];
        float  w  = swid[s];
        float ddx = fmaxf(fmaxf(bb.x - fx3, fx0 - bb.z), 0.0f);
        float ddy = fmaxf(fmaxf(bb.y - fy,  fy  - bb.w), 0.0f);
        float cut = w + 10.0f;
        if (__all((ddx*ddx + ddy*ddy) > cut*cut)) continue;

        float m0 = 1e30f, m1 = 1e30f, m2 = 1e30f, m3 = 1e30f;
        const float4* P4 = (const float4*)(spts + s * NSAMP);
        #pragma unroll
        for (int j = 0; j < NSAMP / 2; ++j) {
            float4 q = P4[j];
            float dy0 = fy - q.y; float t0 = dy0 * dy0;
            float dy1 = fy - q.w; float t1 = dy1 * dy1;
            { float da = fx0 - q.x, db = fx0 - q.z;
              m0 = fminf(fminf(fmaf(da,da,t0), fmaf(db,db,t1)), m0); }
            { float da = fx1 - q.x, db = fx1 - q.z;
              m1 = fminf(fminf(fmaf(da,da,t0), fmaf(db,db,t1)), m1); }
            { float da = fx2 - q.x, db = fx2 - q.z;
              m2 = fminf(fminf(fmaf(da,da,t0), fmaf(db,db,t1)), m2); }
            { float da = fx3 - q.x, db = fx3 - q.z;
              m3 = fminf(fminf(fmaf(da,da,t0), fmaf(db,db,t1)), m3); }
        }

        float4 col = scol[s];
        float a0 = __builtin_amdgcn_rcpf(1.0f + __expf(2.0f * (sqrtf(m0) - w)));
        float a1 = __builtin_amdgcn_rcpf(1.0f + __expf(2.0f * (sqrtf(m1) - w)));
        float a2 = __builtin_amdgcn_rcpf(1.0f + __expf(2.0f * (sqrtf(m2) - w)));
        float a3 = __builtin_amdgcn_rcpf(1.0f + __expf(2.0f * (sqrtf(m3) - w)));

        cr0 = fmaf(a0, col.x - cr0, cr0); cg0 = fmaf(a0, col.y - cg0, cg0); cb0 = fmaf(a0, col.z - cb0, cb0);
        cr1 = fmaf(a1, col.x - cr1, cr1); cg1 = fmaf(a1, col.y - cg1, cg1); cb1 = fmaf(a1, col.z - cb1, cb1);
        cr2 = fmaf(a2, col.x - cr2, cr2); cg2 = fmaf(a2, col.y - cg2, cg2); cb2 = fmaf(a2, col.z - cb2, cb2);
        cr3 = fmaf(a3, col.x - cr3, cr3); cg3 = fmaf(a3, col.y - cg3, cg3); cb3 = fmaf(a3, col.z - cb3, cb3);
    }

    const int base = y * CANVAS + x0;
    ((float4*)(out + 0*HW + base))[0] = make_float4(cr0, cr1, cr2, cr3);
    ((float4*)(out + 1*HW + base))[0] = make_float4(cg0, cg1, cg2, cg3);
    ((float4*)(out + 2*HW + base))[0] = make_float4(cb0, cb1, cb2, cb3);
}

extern "C" void kernel_launch(void* const* d_in, const int* in_sizes, int n_in,
                              void* d_out, int out_size, void* d_ws, size_t ws_size,
                              hipStream_t stream) {
    const float* strokes = (const float*)d_in[0];
    const float* widths  = (const float*)d_in[1];
    const float* colors  = (const float*)d_in[2];
    float* out = (float*)d_out;

    const size_t need = (size_t)NGROUPS * 4 * HW * sizeof(__half);
    if (ws_size >= need) {
        raster_group_kernel<<<dim3(CANVAS, NGROUPS), dim3(TPB), 0, stream>>>(
            strokes, widths, colors, (__half*)d_ws);
        combine_kernel<<<dim3(HW / 4 / 256), dim3(256), 0, stream>>>(
            (const __half*)d_ws, out);
    } else {
        raster_direct_kernel<<<dim3(CANVAS), dim3(128), 0, stream>>>(
            strokes, widths, colors, out);
    }
}

// Round 7
// 22.837 us; speedup vs baseline: 1.4002x; 1.1611x over previous
//
#include <hip/hip_runtime.h>
#include <hip/hip_fp16.h>

#define NSTROKES 64
#define NSAMP    50
#define CANVAS   512
#define HW       (CANVAS * CANVAS)
#define TPB      512   // 1 px/thread, one 512-px row per block, 8 waves
#define NGROUPS  2
#define SPG      (NSTROKES / NGROUPS)   // 32 strokes per group
#define SPW      (SPG / 8)              // 4 strokes per wave (stage A)
#define LSTRIDE  52                     // float2 slots per stroke list

// ---------------------------------------------------------------------------
// Kernel 1: per (row, stroke-group) block -> affine map c -> A*c + B per px.
//  stage A: ballot compaction of row-band samples into LDS lists, sentinel-
//           padded to even length; per-stroke cull float4 (xlo,xhi,w,cnt).
//  stage B: ballot-transposed cull: 1 lane tests 1 stroke vs wave's 64-px
//           span, __ballot -> wave-uniform live mask, iterate set bits only.
// ---------------------------------------------------------------------------
__global__ __launch_bounds__(TPB) void raster_group_kernel(
    const float* __restrict__ strokes,   // (64,4,2)
    const float* __restrict__ widths,    // (64,)
    const float* __restrict__ colors,    // (64,3)
    __half* __restrict__ ws)             // NGROUPS*4*HW halves
{
    __shared__ __align__(16) float2 slist[SPG * LSTRIDE];  // ~13.3 KB
    __shared__ float4 scull[SPG];   // xmin-cut, xmax+cut, w, cnt
    __shared__ float4 scol [SPG];   // r,g,b,pad

    const int tid  = threadIdx.x;
    const int wave = tid >> 6;
    const int lane = tid & 63;
    const int g     = blockIdx.y;
    const int sbase = g * SPG;
    const int y     = blockIdx.x;
    const float fy  = (float)y;

    // ---- stage A: compaction, SPW strokes per wave, lane = sample index
    #pragma unroll
    for (int i = 0; i < SPW; ++i) {
        const int s  = wave * SPW + i;        // local stroke id 0..31
        const int gs = sbase + s;

        float4 a = ((const float4*)strokes)[gs * 2];       // p0x,p0y,p1x,p1y
        float4 b = ((const float4*)strokes)[gs * 2 + 1];   // p2x,p2y,p3x,p3y
        const float S = (float)CANVAS;
        float c0x = a.x * S;
        float c1x = 3.0f * (a.z - a.x) * S;
        float c2x = 3.0f * (b.x - 2.0f * a.z + a.x) * S;
        float c3x = (b.z - 3.0f * b.x + 3.0f * a.z - a.x) * S;
        float c0y = a.y * S;
        float c1y = 3.0f * (a.w - a.y) * S;
        float c2y = 3.0f * (b.y - 2.0f * a.w + a.y) * S;
        float c3y = (b.w - 3.0f * b.y + 3.0f * a.w - a.y) * S;

        float w   = widths[gs];
        float cut = w + 10.0f;                 // alpha <= sigmoid(-20) ~ 2e-9 beyond

        float t  = (float)lane * (1.0f / (float)(NSAMP - 1));
        float px = fmaf(fmaf(fmaf(c3x, t, c2x), t, c1x), t, c0x);
        float py = fmaf(fmaf(fmaf(c3y, t, c2y), t, c1y), t, c0y);

        bool keep = (lane < NSAMP) && (fabsf(py - fy) <= cut);
        unsigned long long mask = __ballot(keep);
        int idx = __popcll(mask & ((1ull << lane) - 1ull));
        if (keep) slist[s * LSTRIDE + idx] = make_float2(px, py);
        // lane 63 never keeps -> its idx == cnt: free sentinel (kills remainder)
        if (lane == 63) slist[s * LSTRIDE + idx] = make_float2(1e15f, 1e15f);

        if (mask) {
            float vmn = keep ? px : 1e30f;
            float vmx = keep ? px : -1e30f;
            #pragma unroll
            for (int off = 32; off; off >>= 1) {
                vmn = fminf(vmn, __shfl_xor(vmn, off));
                vmx = fmaxf(vmx, __shfl_xor(vmx, off));
            }
            if (lane == 0) {
                scull[s] = make_float4(vmn - cut, vmx + cut, w,
                                       (float)__popcll(mask));
                scol [s] = make_float4(colors[3*gs], colors[3*gs+1],
                                       colors[3*gs+2], 0.0f);
            }
        } else if (lane == 0) {
            scull[s] = make_float4(0.0f, 0.0f, w, 0.0f);   // cnt=0 -> culled
        }
    }
    __syncthreads();

    // ---- stage B: ballot-transposed cull + min-dist + affine blend (1 px)
    const float fx      = (float)tid;
    const float span_lo = (float)(wave << 6);
    const float span_hi = span_lo + 63.0f;

    bool alive = false;
    if (lane < SPG) {
        float4 cb = scull[lane];
        alive = (cb.w > 0.0f) && (cb.x <= span_hi) && (cb.y >= span_lo);
    }
    unsigned long long live = __ballot(alive);

    float A = 1.0f, br = 0.0f, bg = 0.0f, bb = 0.0f;

    while (live) {
        const int s = __ffsll(live) - 1;
        live &= live - 1ull;

        float4 cb  = scull[s];     // broadcast LDS read
        float4 col = scol [s];
        const int   kc = (int)cb.w;
        const float w  = cb.z;

        float m = 1e30f;
        const float2* L = slist + s * LSTRIDE;
        for (int j = 0; j < kc; j += 2) {          // sentinel pads odd kc
            float4 q = *(const float4*)(L + j);    // 2 samples, broadcast
            float dy0 = fy - q.y;
            float dy1 = fy - q.w;
            float da  = fx - q.x;
            float db  = fx - q.z;
            m = fminf(fminf(fmaf(da, da, dy0 * dy0),
                            fmaf(db, db, dy1 * dy1)), m);
        }

        float al = __builtin_amdgcn_rcpf(1.0f + __expf(2.0f * (sqrtf(m) - w)));
        A  *= (1.0f - al);
        br  = fmaf(al, col.x - br, br);
        bg  = fmaf(al, col.y - bg, bg);
        bb  = fmaf(al, col.z - bb, bb);
    }

    const int base = y * CANVAS + tid;
    __half* wp = ws + (size_t)g * 4 * HW;
    wp[0*HW + base] = __float2half(A);
    wp[1*HW + base] = __float2half(br);
    wp[2*HW + base] = __float2half(bg);
    wp[3*HW + base] = __float2half(bb);
}

// ---------------------------------------------------------------------------
// Kernel 2: fold the NGROUPS affine maps (in order) onto the white canvas.
// ---------------------------------------------------------------------------
__global__ __launch_bounds__(256) void combine_kernel(
    const __half* __restrict__ ws, float* __restrict__ out)
{
    const int t    = blockIdx.x * 256 + threadIdx.x;   // HW/4 threads
    const int base = t * 4;

    float4 cr = make_float4(1.f,1.f,1.f,1.f);
    float4 cg = make_float4(1.f,1.f,1.f,1.f);
    float4 cb = make_float4(1.f,1.f,1.f,1.f);

    #pragma unroll
    for (int g = 0; g < NGROUPS; ++g) {
        const __half* wp = ws + (size_t)g * 4 * HW;
        float2 Aa = __half22float2(((const __half2*)(wp + 0*HW))[t*2]);
        float2 Ab = __half22float2(((const __half2*)(wp + 0*HW))[t*2+1]);
        float2 Ra = __half22float2(((const __half2*)(wp + 1*HW))[t*2]);
        float2 Rb = __half22float2(((const __half2*)(wp + 1*HW))[t*2+1]);
        float2 Ga = __half22float2(((const __half2*)(wp + 2*HW))[t*2]);
        float2 Gb = __half22float2(((const __half2*)(wp + 2*HW))[t*2+1]);
        float2 Ba = __half22float2(((const __half2*)(wp + 3*HW))[t*2]);
        float2 Bb = __half22float2(((const __half2*)(wp + 3*HW))[t*2+1]);

        cr.x = fmaf(Aa.x, cr.x, Ra.x); cr.y = fmaf(Aa.y, cr.y, Ra.y);
        cr.z = fmaf(Ab.x, cr.z, Rb.x); cr.w = fmaf(Ab.y, cr.w, Rb.y);
        cg.x = fmaf(Aa.x, cg.x, Ga.x); cg.y = fmaf(Aa.y, cg.y, Ga.y);
        cg.z = fmaf(Ab.x, cg.z, Gb.x); cg.w = fmaf(Ab.y, cg.w, Gb.y);
        cb.x = fmaf(Aa.x, cb.x, Ba.x); cb.y = fmaf(Aa.y, cb.y, Ba.y);
        cb.z = fmaf(Ab.x, cb.z, Bb.x); cb.w = fmaf(Ab.y, cb.w, Bb.y);
    }

    ((float4*)(out + 0*HW + base))[0] = cr;
    ((float4*)(out + 1*HW + base))[0] = cg;
    ((float4*)(out + 2*HW + base))[0] = cb;
}

// ---------------------------------------------------------------------------
// Fallback (ws too small): round-1 direct kernel, known-good.
// ---------------------------------------------------------------------------
__global__ __launch_bounds__(128) void raster_direct_kernel(
    const float* __restrict__ strokes, const float* __restrict__ widths,
    const float* __restrict__ colors, float* __restrict__ out)
{
    __shared__ float2 spts[NSTROKES * NSAMP];
    __shared__ float4 sbb [NSTROKES];
    __shared__ float  swid[NSTROKES];
    __shared__ float4 scol[NSTROKES];

    const int tid = threadIdx.x;
    for (int k = tid; k < NSTROKES * NSAMP; k += 128) {
        int s = k / NSAMP;
        int j = k - s * NSAMP;
        float t  = (float)j * (1.0f / (float)(NSAMP - 1));
        float u  = 1.0f - t;
        float b0 = u*u*u, b1 = 3.f*u*u*t, b2 = 3.f*u*t*t, b3 = t*t*t;
        float4 a = ((const float4*)strokes)[s * 2];
        float4 b = ((const float4*)strokes)[s * 2 + 1];
        spts[k] = make_float2((b0*a.x + b1*a.z + b2*b.x + b3*b.z) * (float)CANVAS,
                              (b0*a.y + b1*a.w + b2*b.y + b3*b.w) * (float)CANVAS);
    }
    if (tid < NSTROKES) {
        float4 a = ((const float4*)strokes)[tid * 2];
        float4 b = ((const float4*)strokes)[tid * 2 + 1];
        sbb [tid] = make_float4(fminf(fminf(a.x,a.z),fminf(b.x,b.z)) * (float)CANVAS,
                                fminf(fminf(a.y,a.w),fminf(b.y,b.w)) * (float)CANVAS,
                                fmaxf(fmaxf(a.x,a.z),fmaxf(b.x,b.z)) * (float)CANVAS,
                                fmaxf(fmaxf(a.y,a.w),fmaxf(b.y,b.w)) * (float)CANVAS);
        swid[tid] = widths[tid];
        scol[tid] = make_float4(colors[3*tid], colors[3*tid+1], colors[3*tid+2], 0.0f);
    }
    __syncthreads();

    const int   y   = blockIdx.x;
    const int   x0  = tid * 4;
    const float fy  = (float)y;
    const float fx0 = (float)x0;
    const float fx1 = fx0+1.f, fx2 = fx0+2.f, fx3 = fx0+3.f;

    float cr0=1.f,cg0=1.f,cb0=1.f, cr1=1.f,cg1=1.f,cb1=1.f;
    float cr2=1.f,cg2=1.f,cb2=1.f, cr3=1.f,cg3=1.f,cb3=1.f;

    for (int s = 0; s < NSTROKES; ++s) {
        float4 bb = sbb[s];
        float  w  = swid[s];
        float ddx = fmaxf(fmaxf(bb.x - fx3, fx0 - bb.z), 0.0f);
        float ddy = fmaxf(fmaxf(bb.y - fy,  fy  - bb.w), 0.0f);
        float cut = w + 10.0f;
        if (__all((ddx*ddx + ddy*ddy) > cut*cut)) continue;

        float m0 = 1e30f, m1 = 1e30f, m2 = 1e30f, m3 = 1e30f;
        const float4* P4 = (const float4*)(spts + s * NSAMP);
        #pragma unroll
        for (int j = 0; j < NSAMP / 2; ++j) {
            float4 q = P4[j];
            float dy0 = fy - q.y; float t0 = dy0 * dy0;
            float dy1 = fy - q.w; float t1 = dy1 * dy1;
            { float da = fx0 - q.x, db = fx0 - q.z;
              m0 = fminf(fminf(fmaf(da,da,t0), fmaf(db,db,t1)), m0); }
            { float da = fx1 - q.x, db = fx1 - q.z;
              m1 = fminf(fminf(fmaf(da,da,t0), fmaf(db,db,t1)), m1); }
            { float da = fx2 - q.x, db = fx2 - q.z;
              m2 = fminf(fminf(fmaf(da,da,t0), fmaf(db,db,t1)), m2); }
            { float da = fx3 - q.x, db = fx3 - q.z;
              m3 = fminf(fminf(fmaf(da,da,t0), fmaf(db,db,t1)), m3); }
        }

        float4 col = scol[s];
        float a0 = __builtin_amdgcn_rcpf(1.0f + __expf(2.0f * (sqrtf(m0) - w)));
        float a1 = __builtin_amdgcn_rcpf(1.0f + __expf(2.0f * (sqrtf(m1) - w)));
        float a2 = __builtin_amdgcn_rcpf(1.0f + __expf(2.0f * (sqrtf(m2) - w)));
        float a3 = __builtin_amdgcn_rcpf(1.0f + __expf(2.0f * (sqrtf(m3) - w)));

        cr0 = fmaf(a0, col.x - cr0, cr0); cg0 = fmaf(a0, col.y - cg0, cg0); cb0 = fmaf(a0, col.z - cb0, cb0);
        cr1 = fmaf(a1, col.x - cr1, cr1); cg1 = fmaf(a1, col.y - cg1, cg1); cb1 = fmaf(a1, col.z - cb1, cb1);
        cr2 = fmaf(a2, col.x - cr2, cr2); cg2 = fmaf(a2, col.y - cg2, cg2); cb2 = fmaf(a2, col.z - cb2, cb2);
        cr3 = fmaf(a3, col.x - cr3, cr3); cg3 = fmaf(a3, col.y - cg3, cg3); cb3 = fmaf(a3, col.z - cb3, cb3);
    }

    const int base = y * CANVAS + x0;
    ((float4*)(out + 0*HW + base))[0] = make_float4(cr0, cr1, cr2, cr3);
    ((float4*)(out + 1*HW + base))[0] = make_float4(cg0, cg1, cg2, cg3);
    ((float4*)(out + 2*HW + base))[0] = make_float4(cb0, cb1, cb2, cb3);
}

extern "C" void kernel_launch(void* const* d_in, const int* in_sizes, int n_in,
                              void* d_out, int out_size, void* d_ws, size_t ws_size,
                              hipStream_t stream) {
    const float* strokes = (const float*)d_in[0];
    const float* widths  = (const float*)d_in[1];
    const float* colors  = (const float*)d_in[2];
    float* out = (float*)d_out;

    const size_t need = (size_t)NGROUPS * 4 * HW * sizeof(__half);
    if (ws_size >= need) {
        raster_group_kernel<<<dim3(CANVAS, NGROUPS), dim3(TPB), 0, stream>>>(
            strokes, widths, colors, (__half*)d_ws);
        combine_kernel<<<dim3(HW / 4 / 256), dim3(256), 0, stream>>>(
            (const __half*)d_ws, out);
    } else {
        raster_direct_kernel<<<dim3(CANVAS), dim3(128), 0, stream>>>(
            strokes, widths, colors, out);
    }
}